// Round 6
// baseline (208.980 us; speedup 1.0000x reference)
//
#include <hip/hip_runtime.h>
#include <math.h>

typedef __attribute__((ext_vector_type(8))) short bf16x8;
typedef __attribute__((ext_vector_type(4))) short bf16x4;
typedef __attribute__((ext_vector_type(4))) float f32x4;

#define NROWS 65536
#define RFEAT 256
#define NCOL 80                         // 64 v-cols + ksum col(64) + 15 pad
#define PARTN (RFEAT * NCOL)            // 20480 floats per partial slot
#define NGROUP 16                       // reduce stage-1 groups

// ws byte offsets
#define OFF_PB 0
#define OFF_ZB 32768
#define OFF_P2 73728
#define OFF_VB 1384448
#define OFF_PARTIALS 9773056

// sc = 64^{-1/4} = 2^{-1.5}; ln(ratio) = ln(1/16)
#define SC 0.35355339059327373f
#define LNRATIO -2.772588722239781f

__device__ __forceinline__ unsigned short f2bf(float f) {
    union { float f; unsigned int u; } v; v.f = f;
    unsigned int r = v.u + 0x7FFFu + ((v.u >> 16) & 1u);   // RNE
    return (unsigned short)(r >> 16);
}

// ---------------- prep: P -> Pb (B-frag, sc folded), V -> Vb (bf16 B-frag layout) ----
__global__ __launch_bounds__(256)
void prep_kernel(const float* __restrict__ V, const float* __restrict__ P,
                 unsigned short* __restrict__ Vb, unsigned short* __restrict__ Pb)
{
    const int t = threadIdx.x;
    if (blockIdx.x == 1024) {   // Pb
        const int l = t & 63, g = t >> 6;
        for (int f = g * 8; f < g * 8 + 8; f++) {
            const int kstep = f >> 4, nt = f & 15;
            const float* src = P + (nt * 16 + (l & 15)) * 64 + kstep * 32 + (l >> 4) * 8;
            bf16x8 frag;
            #pragma unroll
            for (int j = 0; j < 8; j++) frag[j] = (short)f2bf(SC * src[j]);
            *(bf16x8*)(Pb + f * 512 + l * 8) = frag;
        }
        return;
    }
    // V chunk: 64 rows, coalesced load -> LDS (bf16) -> frag-gather -> coalesced store
    __shared__ unsigned short vl[64 * 68];
    const int row = t >> 2, c0 = (t & 3) * 16;
    const float4* src = (const float4*)(V + ((size_t)blockIdx.x * 64 + row) * 64 + c0);
    unsigned short* dst = vl + row * 68 + c0;
    #pragma unroll
    for (int jj = 0; jj < 4; jj++) {
        float4 a = src[jj];
        dst[4*jj+0] = f2bf(a.x); dst[4*jj+1] = f2bf(a.y);
        dst[4*jj+2] = f2bf(a.z); dst[4*jj+3] = f2bf(a.w);
    }
    __syncthreads();
    const int l = t & 63;
    #pragma unroll
    for (int h = 0; h < 2; h++) {
        const int f = (t >> 6) * 2 + h;        // 0..7
        const int ks = f >> 2, nt = f & 3;
        const int kb = ks * 32 + (l >> 4) * 8, n = nt * 16 + (l & 15);
        bf16x8 fr;
        #pragma unroll
        for (int j = 0; j < 8; j++) fr[j] = vl[(kb + j) * 68 + n];
        *(bf16x8*)(Vb + (((size_t)blockIdx.x * 2 + ks) * 4 + nt) * 512 + l * 8) = fr;
    }
}

// ---------------- phi of a 64-row chunk -> LDS (bf16), via MFMA ----------------
// rc computed DISTRIBUTED: each wave derives its 16 rows' norms from the same
// elements it loads for its A-fragments (2x shfl_xor cross-group reduce).
// TRANS=true : phi_lds[col*LDP + row]  (A-frags along k-rows, for kv kernel)
// TRANS=false: phi_lds[row*LDP + col]  (A-frags along features, for q kernel)
template<int LDP, bool TRANS>
__device__ __forceinline__ void phi_chunk(const float* __restrict__ X, int chunkBase,
                                          const unsigned short* __restrict__ Pb,
                                          unsigned short* phi_lds, float* rc)
{
    const int t = threadIdx.x, l = t & 63, w = t >> 6;
    // A-frags: wave w owns rows [chunkBase+16w, +16); m = l&15, k = (l>>4)*8 + j (+32 kstep 1)
    const float* ar = X + (size_t)(chunkBase + 16 * w + (l & 15)) * 64 + (l >> 4) * 8;
    bf16x8 a0, a1;
    float ss = 0.f;
    #pragma unroll
    for (int j = 0; j < 8; j++) { float x = ar[j];      ss += x * x; a0[j] = (short)f2bf(x); }
    #pragma unroll
    for (int j = 0; j < 8; j++) { float x = ar[32 + j]; ss += x * x; a1[j] = (short)f2bf(x); }
    ss += __shfl_xor(ss, 16);
    ss += __shfl_xor(ss, 32);            // all 4 lane-groups now hold full ||row||^2
    if (l < 16) rc[16 * w + l] = -0.5f * (SC * SC) * ss + LNRATIO;
    __syncthreads();   // rc ready; all threads done reading previous chunk's phi_lds
    #pragma unroll
    for (int nt = 0; nt < 16; nt++) {
        bf16x8 b0 = *(const bf16x8*)(Pb + nt * 512 + l * 8);
        bf16x8 b1 = *(const bf16x8*)(Pb + (16 + nt) * 512 + l * 8);
        f32x4 acc = (f32x4){0.f, 0.f, 0.f, 0.f};
        acc = __builtin_amdgcn_mfma_f32_16x16x32_bf16(a0, b0, acc, 0, 0, 0);
        acc = __builtin_amdgcn_mfma_f32_16x16x32_bf16(a1, b1, acc, 0, 0, 0);
        const int col = nt * 16 + (l & 15);
        const int r0 = 16 * w + (l >> 4) * 4;
        if (TRANS) {
            bf16x4 pk;   // D rows r0..r0+3 contiguous in TRANS layout -> one b64 store
            #pragma unroll
            for (int reg = 0; reg < 4; reg++)
                pk[reg] = (short)f2bf(__expf(acc[reg] + rc[r0 + reg]));
            *(bf16x4*)(phi_lds + col * LDP + r0) = pk;
        } else {
            #pragma unroll
            for (int reg = 0; reg < 4; reg++)
                phi_lds[(r0 + reg) * LDP + col] = f2bf(__expf(acc[reg] + rc[r0 + reg]));
        }
    }
    __syncthreads();
}

// ---------------- kv_fused: partials = phi(K)^T @ [V | 1] over this block's chunk ----------------
__global__ __launch_bounds__(256, 3)
void kv_fused_kernel(const float* __restrict__ Kp, const unsigned short* __restrict__ Vb,
                     const unsigned short* __restrict__ Pb,
                     float* __restrict__ partials, int chunksPerBlock)
{
    __shared__ unsigned short phi_lds[RFEAT * 72];   // [feat][krow], padded
    __shared__ float rc[64];
    const int t = threadIdx.x, l = t & 63, w = t >> 6;

    f32x4 acc[4][5];
    #pragma unroll
    for (int mt = 0; mt < 4; mt++)
        #pragma unroll
        for (int nt = 0; nt < 5; nt++) acc[mt][nt] = (f32x4){0.f, 0.f, 0.f, 0.f};

    bf16x8 ones;   // B-frag for ksum column: B[k][64]=1, rest 0 -> lanes with (l&15)==0
    #pragma unroll
    for (int j = 0; j < 8; j++) ones[j] = (short)(((l & 15) == 0) ? 0x3F80 : 0);

    const int base = blockIdx.x * chunksPerBlock * 64;
    for (int c = 0; c < chunksPerBlock; c++) {
        const int cb = base + c * 64;
        // Prefetch this chunk's V frags (HBM latency overlaps the phi compute)
        bf16x8 vf[2][4];
        const size_t k32 = (size_t)(cb >> 5);
        #pragma unroll
        for (int ks = 0; ks < 2; ks++)
            #pragma unroll
            for (int nt = 0; nt < 4; nt++)
                vf[ks][nt] = *(const bf16x8*)(Vb + ((k32 + ks) * 4 + nt) * 512 + l * 8);

        phi_chunk<72, true>(Kp, cb, Pb, phi_lds, rc);

        #pragma unroll
        for (int ks = 0; ks < 2; ks++) {
            bf16x8 af[4];   // A = phi(K)^T: m=feature, k=krow; wave w owns feats [64w,+64)
            #pragma unroll
            for (int mt = 0; mt < 4; mt++)
                af[mt] = *(const bf16x8*)(phi_lds + (64 * w + mt * 16 + (l & 15)) * 72
                                          + ks * 32 + (l >> 4) * 8);
            #pragma unroll
            for (int mt = 0; mt < 4; mt++) {
                #pragma unroll
                for (int nt = 0; nt < 4; nt++)
                    acc[mt][nt] = __builtin_amdgcn_mfma_f32_16x16x32_bf16(af[mt], vf[ks][nt], acc[mt][nt], 0, 0, 0);
                acc[mt][4] = __builtin_amdgcn_mfma_f32_16x16x32_bf16(af[mt], ones, acc[mt][4], 0, 0, 0);
            }
        }
    }
    float* slot = partials + (size_t)blockIdx.x * PARTN;
    #pragma unroll
    for (int mt = 0; mt < 4; mt++)
        #pragma unroll
        for (int nt = 0; nt < 5; nt++)
            #pragma unroll
            for (int reg = 0; reg < 4; reg++)
                slot[(64 * w + mt * 16 + (l >> 4) * 4 + reg) * 80 + nt * 16 + (l & 15)] = acc[mt][nt][reg];
}

// ---------------- reduce stage 1: sum a group of slots -> p2[g][20480] ----------------
__global__ __launch_bounds__(256)
void reduce1_kernel(const float* __restrict__ partials, float* __restrict__ p2,
                    int slotsPerGroup)
{
    const int idx = blockIdx.x * 256 + threadIdx.x;   // 80*256 == 20480 exactly
    const int g = blockIdx.y;
    const float* base = partials + (size_t)g * slotsPerGroup * PARTN + idx;
    float s0 = 0.f, s1 = 0.f, s2 = 0.f, s3 = 0.f;
    int b = 0;
    for (; b + 4 <= slotsPerGroup; b += 4) {
        s0 += base[(size_t)(b + 0) * PARTN];
        s1 += base[(size_t)(b + 1) * PARTN];
        s2 += base[(size_t)(b + 2) * PARTN];
        s3 += base[(size_t)(b + 3) * PARTN];
    }
    for (; b < slotsPerGroup; b++) s0 += base[(size_t)b * PARTN];
    p2[(size_t)g * PARTN + idx] = (s0 + s1) + (s2 + s3);
}

// ---------------- reduce stage 2: sum groups -> Zb (bf16, B-frag octet layout) ----------------
// Zb element (m,n) at ushort ((m>>3)*80 + n)*8 + (m&7); col 64 = ksum.
__global__ __launch_bounds__(256)
void reduce2_kernel(const float* __restrict__ p2, unsigned short* __restrict__ Zb, int ngroups)
{
    const int idx = blockIdx.x * 256 + threadIdx.x;
    float s = 0.f;
    for (int g = 0; g < ngroups; g++) s += p2[(size_t)g * PARTN + idx];
    const int m = idx / 80, n = idx - m * 80;
    Zb[((m >> 3) * 80 + n) * 8 + (m & 7)] = f2bf(s);
}

// ---------------- q_out: out = normalize( phi(Q) @ Zb ) ----------------
__global__ __launch_bounds__(256, 4)
void q_out_kernel(const float* __restrict__ Q, const unsigned short* __restrict__ Pb,
                  const unsigned short* __restrict__ Zb, float* __restrict__ out)
{
    __shared__ unsigned short phi_lds[64 * 280];   // [row][feat], stride 280 (2-way banks only)
    __shared__ float rc[64];
    const int t = threadIdx.x, l = t & 63, w = t >> 6;
    const int base = blockIdx.x * 64;

    phi_chunk<280, false>(Q, base, Pb, phi_lds, rc);

    f32x4 acc[5];
    #pragma unroll
    for (int nt = 0; nt < 5; nt++) acc[nt] = (f32x4){0.f, 0.f, 0.f, 0.f};

    #pragma unroll
    for (int ks = 0; ks < 8; ks++) {
        // A = phi(Q): m = qrow (wave w rows 16w..+16), k = feature
        bf16x8 a = *(const bf16x8*)(phi_lds + (16 * w + (l & 15)) * 280 + ks * 32 + (l >> 4) * 8);
        #pragma unroll
        for (int nt = 0; nt < 5; nt++) {
            bf16x8 b = *(const bf16x8*)(Zb + ((ks * 4 + (l >> 4)) * 80 + nt * 16 + (l & 15)) * 8);
            acc[nt] = __builtin_amdgcn_mfma_f32_16x16x32_bf16(a, b, acc[nt], 0, 0, 0);
        }
    }
    // denom = output column 64 -> tile 4, lanes with (l&15)==0; broadcast within 16-group
    float inv[4];
    #pragma unroll
    for (int reg = 0; reg < 4; reg++) {
        float den = __shfl(acc[4][reg], (l & 48));
        inv[reg] = 1.0f / den;
    }
    const int row = base + 16 * w + (l >> 4) * 4;
    #pragma unroll
    for (int nt = 0; nt < 4; nt++)
        #pragma unroll
        for (int reg = 0; reg < 4; reg++)
            out[(size_t)(row + reg) * 64 + nt * 16 + (l & 15)] = acc[nt][reg] * inv[reg];
}

extern "C" void kernel_launch(void* const* d_in, const int* in_sizes, int n_in,
                              void* d_out, int out_size, void* d_ws, size_t ws_size,
                              hipStream_t stream) {
    const float* q = (const float*)d_in[0];
    const float* k = (const float*)d_in[1];
    const float* v = (const float*)d_in[2];
    const float* P = (const float*)d_in[3];
    float* out = (float*)d_out;

    unsigned short* Pb = (unsigned short*)((char*)d_ws + OFF_PB);
    unsigned short* Zb = (unsigned short*)((char*)d_ws + OFF_ZB);
    float* p2          = (float*)((char*)d_ws + OFF_P2);
    unsigned short* Vb = (unsigned short*)((char*)d_ws + OFF_VB);
    float* partials    = (float*)((char*)d_ws + OFF_PARTIALS);

    long avail = ((long)ws_size - OFF_PARTIALS) / (long)(PARTN * 4);
    int NB = 1024;                                  // power of two; 65536/(64*NB) exact
    while (NB > NGROUP && (long)NB > avail) NB >>= 1;
    int chunks = 1024 / NB;
    int ngroups = (NB >= NGROUP) ? NGROUP : NB;
    int spg = NB / ngroups;

    prep_kernel<<<1025, 256, 0, stream>>>(v, P, Vb, Pb);
    kv_fused_kernel<<<NB, 256, 0, stream>>>(k, Vb, Pb, partials, chunks);
    reduce1_kernel<<<dim3(80, ngroups), 256, 0, stream>>>(partials, p2, spg);
    reduce2_kernel<<<80, 256, 0, stream>>>(p2, Zb, ngroups);
    q_out_kernel<<<1024, 256, 0, stream>>>(q, Pb, Zb, out);
}

// Round 7
// 144.347 us; speedup vs baseline: 1.4478x; 1.4478x over previous
//
#include <hip/hip_runtime.h>
#include <math.h>

typedef __attribute__((ext_vector_type(8))) short bf16x8;
typedef __attribute__((ext_vector_type(4))) short bf16x4;
typedef __attribute__((ext_vector_type(4))) float f32x4;

#define NROWS 65536
#define RFEAT 256
#define PARTN 20480                     // floats per partial slot (frag-contiguous layout)
#define NGROUP 16                       // reduce stage-1 groups

// ws byte offsets
#define OFF_PB 0
#define OFF_ZB 32768
#define OFF_P2 73728
#define OFF_VB 1384448
#define OFF_PARTIALS 9773056

// sc = 64^{-1/4} = 2^{-1.5}; ln(ratio) = ln(1/16)
#define SC 0.35355339059327373f
#define LNRATIO -2.772588722239781f

__device__ __forceinline__ unsigned short f2bf(float f) {
    union { float f; unsigned int u; } v; v.f = f;
    unsigned int r = v.u + 0x7FFFu + ((v.u >> 16) & 1u);   // RNE
    return (unsigned short)(r >> 16);
}

// ---------------- prep: P -> Pb (B-frag, sc folded), V -> Vb (bf16 B-frag layout) ----
__global__ __launch_bounds__(256)
void prep_kernel(const float* __restrict__ V, const float* __restrict__ P,
                 unsigned short* __restrict__ Vb, unsigned short* __restrict__ Pb)
{
    const int t = threadIdx.x;
    if (blockIdx.x == 1024) {   // Pb
        const int l = t & 63, g = t >> 6;
        for (int f = g * 8; f < g * 8 + 8; f++) {
            const int kstep = f >> 4, nt = f & 15;
            const float* src = P + (nt * 16 + (l & 15)) * 64 + kstep * 32 + (l >> 4) * 8;
            bf16x8 frag;
            #pragma unroll
            for (int j = 0; j < 8; j++) frag[j] = (short)f2bf(SC * src[j]);
            *(bf16x8*)(Pb + f * 512 + l * 8) = frag;
        }
        return;
    }
    // V chunk: 64 rows, coalesced load -> LDS (bf16) -> frag-gather -> coalesced store
    __shared__ unsigned short vl[64 * 68];
    const int row = t >> 2, c0 = (t & 3) * 16;
    const float4* src = (const float4*)(V + ((size_t)blockIdx.x * 64 + row) * 64 + c0);
    unsigned short* dst = vl + row * 68 + c0;
    #pragma unroll
    for (int jj = 0; jj < 4; jj++) {
        float4 a = src[jj];
        dst[4*jj+0] = f2bf(a.x); dst[4*jj+1] = f2bf(a.y);
        dst[4*jj+2] = f2bf(a.z); dst[4*jj+3] = f2bf(a.w);
    }
    __syncthreads();
    const int l = t & 63;
    #pragma unroll
    for (int h = 0; h < 2; h++) {
        const int f = (t >> 6) * 2 + h;        // 0..7
        const int ks = f >> 2, nt = f & 3;
        const int kb = ks * 32 + (l >> 4) * 8, n = nt * 16 + (l & 15);
        bf16x8 fr;
        #pragma unroll
        for (int j = 0; j < 8; j++) fr[j] = vl[(kb + j) * 68 + n];
        *(bf16x8*)(Vb + (((size_t)blockIdx.x * 2 + ks) * 4 + nt) * 512 + l * 8) = fr;
    }
}

// ---------------- phi of a 64-row chunk -> LDS (bf16), via MFMA ----------------
// rc distributed: each wave derives its 16 rows' norms from its own A-frag loads.
// TRANS=true : phi_lds[col*LDP + row]  (A-frags along k-rows, for kv kernel)
// TRANS=false: phi_lds[row*LDP + col]  (A-frags along features, for q kernel)
template<int LDP, bool TRANS>
__device__ __forceinline__ void phi_chunk(const float* __restrict__ X, int chunkBase,
                                          const unsigned short* __restrict__ Pb,
                                          unsigned short* phi_lds, float* rc)
{
    const int t = threadIdx.x, l = t & 63, w = t >> 6;
    // A-frags: wave w owns rows [chunkBase+16w, +16); m = l&15, k = (l>>4)*8 + j (+32 kstep 1)
    const float* ar = X + (size_t)(chunkBase + 16 * w + (l & 15)) * 64 + (l >> 4) * 8;
    bf16x8 a0, a1;
    float ss = 0.f;
    #pragma unroll
    for (int j = 0; j < 8; j++) { float x = ar[j];      ss += x * x; a0[j] = (short)f2bf(x); }
    #pragma unroll
    for (int j = 0; j < 8; j++) { float x = ar[32 + j]; ss += x * x; a1[j] = (short)f2bf(x); }
    ss += __shfl_xor(ss, 16);
    ss += __shfl_xor(ss, 32);            // all 4 lane-groups now hold full ||row||^2
    if (l < 16) rc[16 * w + l] = -0.5f * (SC * SC) * ss + LNRATIO;
    __syncthreads();   // rc ready; all threads done reading previous chunk's phi_lds
    #pragma unroll
    for (int nt = 0; nt < 16; nt++) {
        bf16x8 b0 = *(const bf16x8*)(Pb + nt * 512 + l * 8);
        bf16x8 b1 = *(const bf16x8*)(Pb + (16 + nt) * 512 + l * 8);
        f32x4 acc = (f32x4){0.f, 0.f, 0.f, 0.f};
        acc = __builtin_amdgcn_mfma_f32_16x16x32_bf16(a0, b0, acc, 0, 0, 0);
        acc = __builtin_amdgcn_mfma_f32_16x16x32_bf16(a1, b1, acc, 0, 0, 0);
        const int col = nt * 16 + (l & 15);
        const int r0 = 16 * w + (l >> 4) * 4;
        if (TRANS) {
            bf16x4 pk;   // D rows r0..r0+3 contiguous in TRANS layout -> one b64 store
            #pragma unroll
            for (int reg = 0; reg < 4; reg++)
                pk[reg] = (short)f2bf(__expf(acc[reg] + rc[r0 + reg]));
            *(bf16x4*)(phi_lds + col * LDP + r0) = pk;
        } else {
            #pragma unroll
            for (int reg = 0; reg < 4; reg++)
                phi_lds[(r0 + reg) * LDP + col] = f2bf(__expf(acc[reg] + rc[r0 + reg]));
        }
    }
    __syncthreads();
}

// ---------------- kv_fused: partials = phi(K)^T @ [V | 1] over this block's chunks ---------
// Partials layout (frag-contiguous, full-cache-line writes):
//   F = ((w*4 + mt)*5 + nt)*256 + l*4 + reg
//   maps to matrix element m = 64w + 16mt + 4(l>>4) + reg, n = 16nt + (l&15).
__global__ __launch_bounds__(256, 2)
void kv_fused_kernel(const float* __restrict__ Kp, const unsigned short* __restrict__ Vb,
                     const unsigned short* __restrict__ Pb,
                     float* __restrict__ partials, int chunksPerBlock)
{
    __shared__ unsigned short phi_lds[RFEAT * 72];   // [feat][krow], padded
    __shared__ float rc[64];
    const int t = threadIdx.x, l = t & 63, w = t >> 6;

    f32x4 acc[4][5];
    #pragma unroll
    for (int mt = 0; mt < 4; mt++)
        #pragma unroll
        for (int nt = 0; nt < 5; nt++) acc[mt][nt] = (f32x4){0.f, 0.f, 0.f, 0.f};

    bf16x8 ones;   // B-frag for ksum column: B[k][64]=1, rest 0 -> lanes with (l&15)==0
    #pragma unroll
    for (int j = 0; j < 8; j++) ones[j] = (short)(((l & 15) == 0) ? 0x3F80 : 0);

    const int base = blockIdx.x * chunksPerBlock * 64;
    for (int c = 0; c < chunksPerBlock; c++) {
        const int cb = base + c * 64;
        // Prefetch this chunk's V frags (HBM latency overlaps the phi compute)
        bf16x8 vf[2][4];
        const size_t k32 = (size_t)(cb >> 5);
        #pragma unroll
        for (int ks = 0; ks < 2; ks++)
            #pragma unroll
            for (int nt = 0; nt < 4; nt++)
                vf[ks][nt] = *(const bf16x8*)(Vb + ((k32 + ks) * 4 + nt) * 512 + l * 8);

        phi_chunk<72, true>(Kp, cb, Pb, phi_lds, rc);

        #pragma unroll
        for (int ks = 0; ks < 2; ks++) {
            bf16x8 af[4];   // A = phi(K)^T: m=feature, k=krow; wave w owns feats [64w,+64)
            #pragma unroll
            for (int mt = 0; mt < 4; mt++)
                af[mt] = *(const bf16x8*)(phi_lds + (64 * w + mt * 16 + (l & 15)) * 72
                                          + ks * 32 + (l >> 4) * 8);
            #pragma unroll
            for (int mt = 0; mt < 4; mt++) {
                #pragma unroll
                for (int nt = 0; nt < 4; nt++)
                    acc[mt][nt] = __builtin_amdgcn_mfma_f32_16x16x32_bf16(af[mt], vf[ks][nt], acc[mt][nt], 0, 0, 0);
                acc[mt][4] = __builtin_amdgcn_mfma_f32_16x16x32_bf16(af[mt], ones, acc[mt][4], 0, 0, 0);
            }
        }
    }
    float* slot = partials + (size_t)blockIdx.x * PARTN;
    #pragma unroll
    for (int mt = 0; mt < 4; mt++)
        #pragma unroll
        for (int nt = 0; nt < 5; nt++)
            *(f32x4*)(slot + (((w * 4 + mt) * 5 + nt) << 8) + l * 4) = acc[mt][nt];
}

// ---------------- reduce stage 1: element-wise sum of a group of slots -> p2 ----------------
__global__ __launch_bounds__(256)
void reduce1_kernel(const float* __restrict__ partials, float* __restrict__ p2,
                    int slotsPerGroup)
{
    const int idx = blockIdx.x * 256 + threadIdx.x;   // 80*256 == 20480 exactly
    const int g = blockIdx.y;
    const float* base = partials + (size_t)g * slotsPerGroup * PARTN + idx;
    float s0 = 0.f, s1 = 0.f, s2 = 0.f, s3 = 0.f;
    int b = 0;
    for (; b + 4 <= slotsPerGroup; b += 4) {
        s0 += base[(size_t)(b + 0) * PARTN];
        s1 += base[(size_t)(b + 1) * PARTN];
        s2 += base[(size_t)(b + 2) * PARTN];
        s3 += base[(size_t)(b + 3) * PARTN];
    }
    for (; b < slotsPerGroup; b++) s0 += base[(size_t)b * PARTN];
    p2[(size_t)g * PARTN + idx] = (s0 + s1) + (s2 + s3);
}

// ---------------- reduce stage 2: sum groups -> Zb (bf16, B-frag octet layout) ----------------
// Invert F -> (m,n); Zb element (m,n) at ushort ((m>>3)*80 + n)*8 + (m&7); col 64 = ksum.
__global__ __launch_bounds__(256)
void reduce2_kernel(const float* __restrict__ p2, unsigned short* __restrict__ Zb, int ngroups)
{
    const int idx = blockIdx.x * 256 + threadIdx.x;
    float s = 0.f;
    for (int g = 0; g < ngroups; g++) s += p2[(size_t)g * PARTN + idx];
    const int tile = idx >> 8, rem = idx & 255;
    const int l = rem >> 2, reg = rem & 3;
    const int nt = tile % 5, wmt = tile / 5;
    const int w = wmt >> 2, mt = wmt & 3;
    const int m = 64 * w + 16 * mt + 4 * (l >> 4) + reg;
    const int n = 16 * nt + (l & 15);
    Zb[((m >> 3) * 80 + n) * 8 + (m & 7)] = f2bf(s);
}

// ---------------- q_out: out = normalize( phi(Q) @ Zb ) ----------------
__global__ __launch_bounds__(256, 4)
void q_out_kernel(const float* __restrict__ Q, const unsigned short* __restrict__ Pb,
                  const unsigned short* __restrict__ Zb, float* __restrict__ out)
{
    __shared__ unsigned short phi_lds[64 * 280];   // [row][feat], stride 280 (2-way banks only)
    __shared__ float rc[64];
    const int t = threadIdx.x, l = t & 63, w = t >> 6;
    const int base = blockIdx.x * 64;

    phi_chunk<280, false>(Q, base, Pb, phi_lds, rc);

    f32x4 acc[5];
    #pragma unroll
    for (int nt = 0; nt < 5; nt++) acc[nt] = (f32x4){0.f, 0.f, 0.f, 0.f};

    #pragma unroll
    for (int ks = 0; ks < 8; ks++) {
        // A = phi(Q): m = qrow (wave w rows 16w..+16), k = feature
        bf16x8 a = *(const bf16x8*)(phi_lds + (16 * w + (l & 15)) * 280 + ks * 32 + (l >> 4) * 8);
        #pragma unroll
        for (int nt = 0; nt < 5; nt++) {
            bf16x8 b = *(const bf16x8*)(Zb + ((ks * 4 + (l >> 4)) * 80 + nt * 16 + (l & 15)) * 8);
            acc[nt] = __builtin_amdgcn_mfma_f32_16x16x32_bf16(a, b, acc[nt], 0, 0, 0);
        }
    }
    // denom = output column 64 -> tile 4, lanes with (l&15)==0; broadcast within 16-group
    float inv[4];
    #pragma unroll
    for (int reg = 0; reg < 4; reg++) {
        float den = __shfl(acc[4][reg], (l & 48));
        inv[reg] = 1.0f / den;
    }
    const int row = base + 16 * w + (l >> 4) * 4;
    #pragma unroll
    for (int nt = 0; nt < 4; nt++)
        #pragma unroll
        for (int reg = 0; reg < 4; reg++)
            out[(size_t)(row + reg) * 64 + nt * 16 + (l & 15)] = acc[nt][reg] * inv[reg];
}

extern "C" void kernel_launch(void* const* d_in, const int* in_sizes, int n_in,
                              void* d_out, int out_size, void* d_ws, size_t ws_size,
                              hipStream_t stream) {
    const float* q = (const float*)d_in[0];
    const float* k = (const float*)d_in[1];
    const float* v = (const float*)d_in[2];
    const float* P = (const float*)d_in[3];
    float* out = (float*)d_out;

    unsigned short* Pb = (unsigned short*)((char*)d_ws + OFF_PB);
    unsigned short* Zb = (unsigned short*)((char*)d_ws + OFF_ZB);
    float* p2          = (float*)((char*)d_ws + OFF_P2);
    unsigned short* Vb = (unsigned short*)((char*)d_ws + OFF_VB);
    float* partials    = (float*)((char*)d_ws + OFF_PARTIALS);

    long avail = ((long)ws_size - OFF_PARTIALS) / (long)(PARTN * 4);
    int NB = 256;                                   // power of two; 65536/(64*NB) exact
    while (NB > NGROUP && (long)NB > avail) NB >>= 1;
    int chunks = 1024 / NB;
    int ngroups = (NB >= NGROUP) ? NGROUP : NB;
    int spg = NB / ngroups;

    prep_kernel<<<1025, 256, 0, stream>>>(v, P, Vb, Pb);
    kv_fused_kernel<<<NB, 256, 0, stream>>>(k, Vb, Pb, partials, chunks);
    reduce1_kernel<<<dim3(80, ngroups), 256, 0, stream>>>(partials, p2, spg);
    reduce2_kernel<<<80, 256, 0, stream>>>(p2, Zb, ngroups);
    q_out_kernel<<<1024, 256, 0, stream>>>(q, Pb, Zb, out);
}

// Round 8
// 142.008 us; speedup vs baseline: 1.4716x; 1.0165x over previous
//
#include <hip/hip_runtime.h>
#include <math.h>

typedef __attribute__((ext_vector_type(8))) short bf16x8;
typedef __attribute__((ext_vector_type(4))) short bf16x4;
typedef __attribute__((ext_vector_type(4))) float f32x4;

#define RFEAT 256
#define PARTN 20480                     // floats per partial slot (frag-contiguous layout)
#define NGROUP 16                       // reduce stage-1 groups
#define NB_KV 512                       // kv blocks (2 chunks each)

// ws byte offsets
#define OFF_PB 0
#define OFF_ZB 32768
#define OFF_P2 73728
#define OFF_VB 1384448
#define OFF_PARTIALS 9773056

// sc = 64^{-1/4} = 2^{-1.5}; ln(ratio) = ln(1/16)
#define SC 0.35355339059327373f
#define LNRATIO -2.772588722239781f

struct Raw { float x[16]; };            // one chunk's per-thread raw A-frag data

__device__ __forceinline__ unsigned short f2bf(float f) {
    union { float f; unsigned int u; } v; v.f = f;
    unsigned int r = v.u + 0x7FFFu + ((v.u >> 16) & 1u);   // RNE
    return (unsigned short)(r >> 16);
}

// ---------------- prep: P -> Pb (B-frag, sc folded), V -> Vb (bf16 B-frag layout) ----
__global__ __launch_bounds__(256)
void prep_kernel(const float* __restrict__ V, const float* __restrict__ P,
                 unsigned short* __restrict__ Vb, unsigned short* __restrict__ Pb)
{
    const int t = threadIdx.x;
    if (blockIdx.x == 1024) {   // Pb
        const int l = t & 63, g = t >> 6;
        for (int f = g * 8; f < g * 8 + 8; f++) {
            const int kstep = f >> 4, nt = f & 15;
            const float* src = P + (nt * 16 + (l & 15)) * 64 + kstep * 32 + (l >> 4) * 8;
            bf16x8 frag;
            #pragma unroll
            for (int j = 0; j < 8; j++) frag[j] = (short)f2bf(SC * src[j]);
            *(bf16x8*)(Pb + f * 512 + l * 8) = frag;
        }
        return;
    }
    // V chunk: 64 rows, coalesced load -> LDS (bf16) -> frag-gather -> coalesced store
    __shared__ unsigned short vl[64 * 68];
    const int row = t >> 2, c0 = (t & 3) * 16;
    const float4* src = (const float4*)(V + ((size_t)blockIdx.x * 64 + row) * 64 + c0);
    unsigned short* dst = vl + row * 68 + c0;
    #pragma unroll
    for (int jj = 0; jj < 4; jj++) {
        float4 a = src[jj];
        dst[4*jj+0] = f2bf(a.x); dst[4*jj+1] = f2bf(a.y);
        dst[4*jj+2] = f2bf(a.z); dst[4*jj+3] = f2bf(a.w);
    }
    __syncthreads();
    const int l = t & 63;
    #pragma unroll
    for (int h = 0; h < 2; h++) {
        const int f = (t >> 6) * 2 + h;        // 0..7
        const int ks = f >> 2, nt = f & 3;
        const int kb = ks * 32 + (l >> 4) * 8, n = nt * 16 + (l & 15);
        bf16x8 fr;
        #pragma unroll
        for (int j = 0; j < 8; j++) fr[j] = vl[(kb + j) * 68 + n];
        *(bf16x8*)(Vb + (((size_t)blockIdx.x * 2 + ks) * 4 + nt) * 512 + l * 8) = fr;
    }
}

// ---------------- raw chunk load (issues 2x32B global loads; no waits until use) --------
__device__ __forceinline__ Raw load_chunk(const float* __restrict__ X, int chunkBase,
                                          int l, int w)
{
    const float* ar = X + (size_t)(chunkBase + 16 * w + (l & 15)) * 64 + (l >> 4) * 8;
    Raw r;
    #pragma unroll
    for (int j = 0; j < 8; j++) r.x[j] = ar[j];
    #pragma unroll
    for (int j = 0; j < 8; j++) r.x[8 + j] = ar[32 + j];
    return r;
}

// ---------------- phi of a loaded chunk -> LDS (bf16), via MFMA ----------------
// TRANS=true : phi_lds[col*LDP + row]  (A-frags along k-rows, for kv kernel)
// TRANS=false: phi_lds[row*LDP + col]  (A-frags along features, for q kernel)
template<int LDP, bool TRANS>
__device__ __forceinline__ void phi_process(const Raw& r,
                                            const unsigned short* __restrict__ Pb,
                                            unsigned short* phi_lds, float* rc,
                                            int l, int w)
{
    bf16x8 a0, a1;
    float ss = 0.f;
    #pragma unroll
    for (int j = 0; j < 8; j++) { float x = r.x[j];     ss += x * x; a0[j] = (short)f2bf(x); }
    #pragma unroll
    for (int j = 0; j < 8; j++) { float x = r.x[8 + j]; ss += x * x; a1[j] = (short)f2bf(x); }
    ss += __shfl_xor(ss, 16);
    ss += __shfl_xor(ss, 32);            // all 4 lane-groups hold full ||row||^2
    if (l < 16) rc[16 * w + l] = -0.5f * (SC * SC) * ss + LNRATIO;
    __syncthreads();   // rc ready; all threads done reading previous chunk's phi_lds
    #pragma unroll
    for (int nt = 0; nt < 16; nt++) {
        bf16x8 b0 = *(const bf16x8*)(Pb + nt * 512 + l * 8);
        bf16x8 b1 = *(const bf16x8*)(Pb + (16 + nt) * 512 + l * 8);
        f32x4 acc = (f32x4){0.f, 0.f, 0.f, 0.f};
        acc = __builtin_amdgcn_mfma_f32_16x16x32_bf16(a0, b0, acc, 0, 0, 0);
        acc = __builtin_amdgcn_mfma_f32_16x16x32_bf16(a1, b1, acc, 0, 0, 0);
        const int col = nt * 16 + (l & 15);
        const int r0 = 16 * w + (l >> 4) * 4;
        if (TRANS) {
            bf16x4 pk;   // D rows r0..r0+3 contiguous in TRANS layout -> one b64 store
            #pragma unroll
            for (int reg = 0; reg < 4; reg++)
                pk[reg] = (short)f2bf(__expf(acc[reg] + rc[r0 + reg]));
            *(bf16x4*)(phi_lds + col * LDP + r0) = pk;
        } else {
            #pragma unroll
            for (int reg = 0; reg < 4; reg++)
                phi_lds[(r0 + reg) * LDP + col] = f2bf(__expf(acc[reg] + rc[r0 + reg]));
        }
    }
    __syncthreads();
}

// ---------------- kv_fused: partials = phi(K)^T @ [V | 1], 2-chunk pipelined -------------
// Partials layout (frag-contiguous): F = ((w*4+mt)*5+nt)*256 + l*4 + reg
//   -> matrix element m = 64w+16mt+4(l>>4)+reg, n = 16nt+(l&15).
__global__ __launch_bounds__(256, 2)
void kv_fused_kernel(const float* __restrict__ Kp, const unsigned short* __restrict__ Vb,
                     const unsigned short* __restrict__ Pb,
                     float* __restrict__ partials)
{
    __shared__ unsigned short phi_lds[RFEAT * 72];   // [feat][krow], padded
    __shared__ float rc[64];
    const int t = threadIdx.x, l = t & 63, w = t >> 6;

    f32x4 acc[4][5];
    #pragma unroll
    for (int mt = 0; mt < 4; mt++)
        #pragma unroll
        for (int nt = 0; nt < 5; nt++) acc[mt][nt] = (f32x4){0.f, 0.f, 0.f, 0.f};

    bf16x8 ones;   // B-frag for ksum column: B[k][64]=1, rest 0 -> lanes with (l&15)==0
    #pragma unroll
    for (int j = 0; j < 8; j++) ones[j] = (short)(((l & 15) == 0) ? 0x3F80 : 0);

    const int base = blockIdx.x * 128;

    // ---- issue ALL global loads for both chunks up front (one vmcnt queue) ----
    Raw raw0 = load_chunk(Kp, base, l, w);
    Raw raw1 = load_chunk(Kp, base + 64, l, w);
    bf16x8 vf0[2][4], vf1[2][4];
    {
        const size_t k32a = (size_t)(base >> 5), k32b = k32a + 2;
        #pragma unroll
        for (int ks = 0; ks < 2; ks++)
            #pragma unroll
            for (int nt = 0; nt < 4; nt++) {
                vf0[ks][nt] = *(const bf16x8*)(Vb + ((k32a + ks) * 4 + nt) * 512 + l * 8);
                vf1[ks][nt] = *(const bf16x8*)(Vb + ((k32b + ks) * 4 + nt) * 512 + l * 8);
            }
    }

    #pragma unroll
    for (int c = 0; c < 2; c++) {
        phi_process<72, true>(c ? raw1 : raw0, Pb, phi_lds, rc, l, w);
        #pragma unroll
        for (int ks = 0; ks < 2; ks++) {
            bf16x8 af[4];   // A = phi(K)^T: m=feature, k=krow; wave w owns feats [64w,+64)
            #pragma unroll
            for (int mt = 0; mt < 4; mt++)
                af[mt] = *(const bf16x8*)(phi_lds + (64 * w + mt * 16 + (l & 15)) * 72
                                          + ks * 32 + (l >> 4) * 8);
            #pragma unroll
            for (int mt = 0; mt < 4; mt++) {
                #pragma unroll
                for (int nt = 0; nt < 4; nt++)
                    acc[mt][nt] = __builtin_amdgcn_mfma_f32_16x16x32_bf16(
                        af[mt], c ? vf1[ks][nt] : vf0[ks][nt], acc[mt][nt], 0, 0, 0);
                acc[mt][4] = __builtin_amdgcn_mfma_f32_16x16x32_bf16(af[mt], ones, acc[mt][4], 0, 0, 0);
            }
        }
    }

    float* slot = partials + (size_t)blockIdx.x * PARTN;
    #pragma unroll
    for (int mt = 0; mt < 4; mt++)
        #pragma unroll
        for (int nt = 0; nt < 5; nt++)
            *(f32x4*)(slot + (((w * 4 + mt) * 5 + nt) << 8) + l * 4) = acc[mt][nt];
}

// ---------------- reduce stage 1: element-wise sum of a group of slots -> p2 ----------------
__global__ __launch_bounds__(256)
void reduce1_kernel(const float* __restrict__ partials, float* __restrict__ p2,
                    int slotsPerGroup)
{
    const int idx = blockIdx.x * 256 + threadIdx.x;   // 80*256 == 20480 exactly
    const int g = blockIdx.y;
    const float* base = partials + (size_t)g * slotsPerGroup * PARTN + idx;
    float s0 = 0.f, s1 = 0.f, s2 = 0.f, s3 = 0.f;
    int b = 0;
    for (; b + 4 <= slotsPerGroup; b += 4) {
        s0 += base[(size_t)(b + 0) * PARTN];
        s1 += base[(size_t)(b + 1) * PARTN];
        s2 += base[(size_t)(b + 2) * PARTN];
        s3 += base[(size_t)(b + 3) * PARTN];
    }
    for (; b < slotsPerGroup; b++) s0 += base[(size_t)b * PARTN];
    p2[(size_t)g * PARTN + idx] = (s0 + s1) + (s2 + s3);
}

// ---------------- reduce stage 2: sum groups -> Zb (bf16, B-frag octet layout) ----------------
// Invert F -> (m,n); Zb element (m,n) at ushort ((m>>3)*80 + n)*8 + (m&7); col 64 = ksum.
__global__ __launch_bounds__(256)
void reduce2_kernel(const float* __restrict__ p2, unsigned short* __restrict__ Zb, int ngroups)
{
    const int idx = blockIdx.x * 256 + threadIdx.x;
    float s = 0.f;
    for (int g = 0; g < ngroups; g++) s += p2[(size_t)g * PARTN + idx];
    const int tile = idx >> 8, rem = idx & 255;
    const int l = rem >> 2, reg = rem & 3;
    const int nt = tile % 5, wmt = tile / 5;
    const int w = wmt >> 2, mt = wmt & 3;
    const int m = 64 * w + 16 * mt + 4 * (l >> 4) + reg;
    const int n = 16 * nt + (l & 15);
    Zb[((m >> 3) * 80 + n) * 8 + (m & 7)] = f2bf(s);
}

// ---------------- q_out GEMM+store for one chunk (phi already in LDS) ----------------
__device__ __forceinline__ void q_gemm_store(const unsigned short* phi_lds,
                                             const unsigned short* __restrict__ Zb,
                                             float* __restrict__ out, int base,
                                             int l, int w)
{
    f32x4 acc[5];
    #pragma unroll
    for (int nt = 0; nt < 5; nt++) acc[nt] = (f32x4){0.f, 0.f, 0.f, 0.f};
    #pragma unroll
    for (int ks = 0; ks < 8; ks++) {
        bf16x8 a = *(const bf16x8*)(phi_lds + (16 * w + (l & 15)) * 280 + ks * 32 + (l >> 4) * 8);
        #pragma unroll
        for (int nt = 0; nt < 5; nt++) {
            bf16x8 b = *(const bf16x8*)(Zb + ((ks * 4 + (l >> 4)) * 80 + nt * 16 + (l & 15)) * 8);
            acc[nt] = __builtin_amdgcn_mfma_f32_16x16x32_bf16(a, b, acc[nt], 0, 0, 0);
        }
    }
    float inv[4];
    #pragma unroll
    for (int reg = 0; reg < 4; reg++) {
        float den = __shfl(acc[4][reg], (l & 48));   // denom col 64 -> lanes (l&15)==0
        inv[reg] = 1.0f / den;
    }
    const int row = base + 16 * w + (l >> 4) * 4;
    #pragma unroll
    for (int nt = 0; nt < 4; nt++)
        #pragma unroll
        for (int reg = 0; reg < 4; reg++)
            out[(size_t)(row + reg) * 64 + nt * 16 + (l & 15)] = acc[nt][reg] * inv[reg];
}

// ---------------- q_out: out = normalize( phi(Q) @ Zb ), 2-chunk pipelined ----------------
__global__ __launch_bounds__(256, 4)
void q_out_kernel(const float* __restrict__ Q, const unsigned short* __restrict__ Pb,
                  const unsigned short* __restrict__ Zb, float* __restrict__ out)
{
    __shared__ unsigned short phi_lds[64 * 280];   // [row][feat], stride 280 (2-way banks)
    __shared__ float rc[64];
    const int t = threadIdx.x, l = t & 63, w = t >> 6;
    const int base = blockIdx.x * 128;

    // issue both chunks' global loads up front
    Raw raw0 = load_chunk(Q, base, l, w);
    Raw raw1 = load_chunk(Q, base + 64, l, w);

    phi_process<280, false>(raw0, Pb, phi_lds, rc, l, w);
    q_gemm_store(phi_lds, Zb, out, base, l, w);        // chunk-0 stores overlap chunk-1 phi
    __syncthreads();                                   // phi_lds reads done before rewrite
    phi_process<280, false>(raw1, Pb, phi_lds, rc, l, w);
    q_gemm_store(phi_lds, Zb, out, base + 64, l, w);
}

extern "C" void kernel_launch(void* const* d_in, const int* in_sizes, int n_in,
                              void* d_out, int out_size, void* d_ws, size_t ws_size,
                              hipStream_t stream) {
    const float* q = (const float*)d_in[0];
    const float* k = (const float*)d_in[1];
    const float* v = (const float*)d_in[2];
    const float* P = (const float*)d_in[3];
    float* out = (float*)d_out;

    unsigned short* Pb = (unsigned short*)((char*)d_ws + OFF_PB);
    unsigned short* Zb = (unsigned short*)((char*)d_ws + OFF_ZB);
    float* p2          = (float*)((char*)d_ws + OFF_P2);
    unsigned short* Vb = (unsigned short*)((char*)d_ws + OFF_VB);
    float* partials    = (float*)((char*)d_ws + OFF_PARTIALS);

    prep_kernel<<<1025, 256, 0, stream>>>(v, P, Vb, Pb);
    kv_fused_kernel<<<NB_KV, 256, 0, stream>>>(k, Vb, Pb, partials);
    reduce1_kernel<<<dim3(80, NGROUP), 256, 0, stream>>>(partials, p2, NB_KV / NGROUP);
    reduce2_kernel<<<80, 256, 0, stream>>>(p2, Zb, NGROUP);
    q_out_kernel<<<512, 256, 0, stream>>>(q, Pb, Zb, out);
}